// Round 1
// baseline (1410.458 us; speedup 1.0000x reference)
//
#include <hip/hip_runtime.h>
#include <hip/hip_bf16.h>

// S4D regressor: B=32, L=4096, C=128, N=64, DEPTH=4, OUT=1, fp32 throughout.
// Strategy (round 1, correctness-first):
//   y[b,l,c] = sum_{j<=l} K[c,j] x[b,l-j,c]  ==  diagonal complex recurrence
//   s = lam*s + x ; y = 2*Re(sum_n Cbar_n * s_n)
// Implemented as: precompute (lam, 2*Cbar) -> transpose x to [B,C,L] ->
// per layer: recurrent ssm kernel (wave per (b,c), lane per mode n) fusing
// skip+residual, then LayerNorm over C (final layer fuses head projection).
// Workspace: 2 * B*C*L fp32 ping-pong buffers + small tables  (~135 MB).

#define BB     32
#define LL     4096
#define CC     128
#define NN     64
#define DEPTH_ 4
#define EPSV   1e-5f

// ---------------------------------------------------------------------------
// Per (d,c,n): lam = exp(dt*A), cb2 = 2 * (C_re + i C_im) * (lam - 1)/A
// ---------------------------------------------------------------------------
__global__ __launch_bounds__(64) void precompute_kernel(
    const float* __restrict__ log_dt, const float* __restrict__ A_real,
    const float* __restrict__ A_imag, const float* __restrict__ C_re,
    const float* __restrict__ C_im, float2* __restrict__ lam,
    float2* __restrict__ cb2)
{
    int d = blockIdx.y, c = blockIdx.x, n = threadIdx.x;
    float dt  = expf(log_dt[d * CC + c]);
    int  idx  = (d * CC + c) * NN + n;
    float Ar  = -expf(A_real[idx]);
    float Ai  = A_imag[idx];
    float dtr = dt * Ar, dti = dt * Ai;
    float e   = expf(dtr);
    float lr  = e * cosf(dti);
    float li  = e * sinf(dti);
    // (lam - 1) / A  =  (lam-1) * conj(A) / |A|^2
    float m    = Ar * Ar + Ai * Ai;
    float inv  = 1.0f / m;
    float numr = lr - 1.0f, numi = li;
    float br   = (numr * Ar + numi * Ai) * inv;
    float bi   = (numi * Ar - numr * Ai) * inv;
    float cre  = C_re[idx], cim = C_im[idx];
    lam[idx] = make_float2(lr, li);
    cb2[idx] = make_float2(2.0f * (cre * br - cim * bi),
                           2.0f * (cre * bi + cim * br));
}

// ---------------------------------------------------------------------------
// x [B][L][C]  ->  xt [B][C][L]   (64x64 tiles through padded LDS)
// ---------------------------------------------------------------------------
__global__ __launch_bounds__(256) void transpose_kernel(
    const float* __restrict__ x, float* __restrict__ xt)
{
    __shared__ float t[64][65];
    int ct = blockIdx.x;          // 0..C/64-1
    int lt = blockIdx.y;          // 0..L/64-1
    int b  = blockIdx.z;          // 0..B-1
    int tx = threadIdx.x & 63;
    int ty = threadIdx.x >> 6;    // 0..3
    const size_t xbase = ((size_t)b * LL + (size_t)lt * 64) * CC + (size_t)ct * 64;
#pragma unroll
    for (int i = 0; i < 16; ++i)
        t[ty + 4 * i][tx] = x[xbase + (size_t)(ty + 4 * i) * CC + tx];
    __syncthreads();
    const size_t obase = ((size_t)b * CC + (size_t)ct * 64) * LL + (size_t)lt * 64;
#pragma unroll
    for (int i = 0; i < 16; ++i)
        xt[obase + (size_t)(ty + 4 * i) * LL + tx] = t[tx][ty + 4 * i];
}

// ---------------------------------------------------------------------------
// One wave per (b,c); lane n holds complex state for mode n.
// vout = conv(x,K) + (Dskip+1)*x   (skip + residual fused), layout [B][C][L].
// ---------------------------------------------------------------------------
__global__ __launch_bounds__(64) void ssm_kernel(
    const float* __restrict__ xin, float* __restrict__ vout,
    const float2* __restrict__ lam, const float2* __restrict__ cb2,
    const float* __restrict__ Dskip)
{
    int bc = blockIdx.x;            // b*C + c
    int c  = bc & (CC - 1);
    int n  = threadIdx.x;
    float2 l2 = lam[c * NN + n];
    float2 c2 = cb2[c * NN + n];
    float lr = l2.x, li = l2.y, cbr = c2.x, cbi = c2.y;
    float dsk = Dskip[c] + 1.0f;
    const float* xp = xin  + (size_t)bc * LL;
    float*       vp = vout + (size_t)bc * LL;

    __shared__ float xs[64];
    __shared__ float cs[64 * 65];   // [t][n] padded: bank = (t+n)%32, conflict-free

    float sr = 0.0f, si = 0.0f;
    for (int l0 = 0; l0 < LL; l0 += 64) {
        xs[n] = xp[l0 + n];                 // coalesced 256B
        __syncthreads();
#pragma unroll 8
        for (int t = 0; t < 64; ++t) {
            float xv  = xs[t];              // LDS broadcast
            float nsr = fmaf(lr, sr, fmaf(-li, si, xv));
            float nsi = fmaf(li, sr, lr * si);
            sr = nsr; si = nsi;
            cs[t * 65 + n] = fmaf(cbr, sr, -(cbi * si));  // 2*Re(Cbar*s) part
        }
        __syncthreads();
        // lane n reduces row n (output timestep l0+n) over the 64 modes
        float acc = 0.0f;
#pragma unroll 16
        for (int j = 0; j < 64; ++j) acc += cs[n * 65 + j];
        vp[l0 + n] = acc + dsk * xs[n];
        __syncthreads();
    }
}

// ---------------------------------------------------------------------------
// LayerNorm over C in [B][C][L] layout. Block = (b, 64-wide l tile).
// isfinal: fuse head projection, write d_out [B][L].
// ---------------------------------------------------------------------------
__global__ __launch_bounds__(256) void ln_kernel(
    const float* __restrict__ v, float* __restrict__ outx,
    const float* __restrict__ w, const float* __restrict__ bta,
    const float* __restrict__ headw, const float* __restrict__ headb,
    float* __restrict__ fout, int isfinal)
{
    __shared__ float tile[CC][65];
    __shared__ float r1[4][64];
    __shared__ float r2[4][64];
    __shared__ float mrs[2][64];
    int b    = blockIdx.y;
    int l0   = blockIdx.x * 64;
    int lane = threadIdx.x & 63;
    int cg   = threadIdx.x >> 6;     // 0..3
    float sum = 0.0f, sq = 0.0f;
#pragma unroll
    for (int ci = 0; ci < 32; ++ci) {
        int c = cg * 32 + ci;
        float val = v[((size_t)b * CC + c) * LL + l0 + lane];
        tile[c][lane] = val;
        sum += val;
        sq = fmaf(val, val, sq);
    }
    r1[cg][lane] = sum;
    r2[cg][lane] = sq;
    __syncthreads();
    if (cg == 0) {
        float s = r1[0][lane] + r1[1][lane] + r1[2][lane] + r1[3][lane];
        float q = r2[0][lane] + r2[1][lane] + r2[2][lane] + r2[3][lane];
        float mean = s * (1.0f / CC);
        float var  = q * (1.0f / CC) - mean * mean;
        mrs[0][lane] = mean;
        mrs[1][lane] = rsqrtf(var + EPSV);
    }
    __syncthreads();
    float mean = mrs[0][lane], rstd = mrs[1][lane];
    if (!isfinal) {
#pragma unroll
        for (int ci = 0; ci < 32; ++ci) {
            int c = cg * 32 + ci;
            float o = (tile[c][lane] - mean) * rstd * w[c] + bta[c];
            outx[((size_t)b * CC + c) * LL + l0 + lane] = o;
        }
    } else {
        float h = 0.0f;
#pragma unroll
        for (int ci = 0; ci < 32; ++ci) {
            int c = cg * 32 + ci;
            float o = (tile[c][lane] - mean) * rstd * w[c] + bta[c];
            h = fmaf(o, headw[c], h);
        }
        __syncthreads();          // r1 reuse safe-guard
        r1[cg][lane] = h;
        __syncthreads();
        if (cg == 0)
            fout[(size_t)b * LL + l0 + lane] =
                r1[0][lane] + r1[1][lane] + r1[2][lane] + r1[3][lane] + headb[0];
    }
}

// ---------------------------------------------------------------------------
extern "C" void kernel_launch(void* const* d_in, const int* in_sizes, int n_in,
                              void* d_out, int out_size, void* d_ws, size_t ws_size,
                              hipStream_t stream)
{
    const float* x      = (const float*)d_in[0];
    const float* log_dt = (const float*)d_in[1];
    const float* A_real = (const float*)d_in[2];
    const float* A_imag = (const float*)d_in[3];
    const float* C_re   = (const float*)d_in[4];
    const float* C_im   = (const float*)d_in[5];
    const float* Dskip  = (const float*)d_in[6];
    const float* norm_w = (const float*)d_in[7];
    const float* norm_b = (const float*)d_in[8];
    const float* head_w = (const float*)d_in[9];
    const float* head_b = (const float*)d_in[10];
    float* out = (float*)d_out;

    const size_t planeSz = (size_t)BB * CC * LL;       // 16.8M floats
    float*  bufA = (float*)d_ws;
    float*  bufB = bufA + planeSz;
    float2* lam  = (float2*)(bufB + planeSz);
    float2* cb2  = lam + (size_t)DEPTH_ * CC * NN;
    // total ws: 2*planeSz*4 + 2*DEPTH*C*N*8 bytes ~= 135 MB

    precompute_kernel<<<dim3(CC, DEPTH_), 64, 0, stream>>>(
        log_dt, A_real, A_imag, C_re, C_im, lam, cb2);
    transpose_kernel<<<dim3(CC / 64, LL / 64, BB), 256, 0, stream>>>(x, bufA);

    for (int d = 0; d < DEPTH_; ++d) {
        ssm_kernel<<<BB * CC, 64, 0, stream>>>(
            bufA, bufB, lam + (size_t)d * CC * NN, cb2 + (size_t)d * CC * NN,
            Dskip + d * CC);
        ln_kernel<<<dim3(LL / 64, BB), 256, 0, stream>>>(
            bufB, bufA, norm_w + d * CC, norm_b + d * CC,
            head_w, head_b, out, (d == DEPTH_ - 1) ? 1 : 0);
    }
}

// Round 2
// 283.156 us; speedup vs baseline: 4.9812x; 4.9812x over previous
//
#include <hip/hip_runtime.h>
#include <hip/hip_bf16.h>

// S4D regressor, chunked-scan MFMA formulation.
// B=32, L=4096, C=128, N=64, DEPTH=4, OUT=1.
// Per (b,c): chunk T=64. y = Toeplitz(Kloc)@x  (K=64, skip folded into diag)
//            P_k = Vr @ x_chunk (K=64) ; s_k = lam^64 s_{k-1} + P_k (in-LDS scan)
//            y += Wr @ s_{k-1}  (K=128)  -> fused K=192 GEMM with Toeplitz part.
// Weights per channel precomputed in MFMA-frag-packed layout (lane-contiguous).
// Activations bf16 [B][C][L]; accumulation fp32. ws ~= 90 MB.

#define BB     32
#define LL     4096
#define CC     128
#define NN     64
#define DEPTH_ 4
#define EPSV   1e-5f

typedef __attribute__((ext_vector_type(8))) short short8;
typedef __attribute__((ext_vector_type(4))) float f32x4;
typedef __hip_bfloat16 bf16;

#define MFMA(a, b, c) __builtin_amdgcn_mfma_f32_16x16x32_bf16(a, b, c, 0, 0, 0)

__device__ __forceinline__ bf16 tobf(float x) { return __float2bfloat16(x); }

// ---------------------------------------------------------------------------
// P0: per (d,c,n): lam=exp(dt*A), dta=dt*A, cb2=2*C*(lam-1)/A, lamT=lam^64
// ---------------------------------------------------------------------------
__global__ __launch_bounds__(64) void p0_kernel(
    const float* __restrict__ log_dt, const float* __restrict__ A_real,
    const float* __restrict__ A_imag, const float* __restrict__ C_re,
    const float* __restrict__ C_im, float2* __restrict__ lam,
    float2* __restrict__ dta, float2* __restrict__ cb2,
    float2* __restrict__ lamT)
{
    int d = blockIdx.y, c = blockIdx.x, n = threadIdx.x;
    int idx = (d * CC + c) * NN + n;
    float dt  = expf(log_dt[d * CC + c]);
    float Ar  = -expf(A_real[idx]);
    float Ai  = A_imag[idx];
    float dtr = dt * Ar, dti = dt * Ai;
    float e   = expf(dtr);
    float lr  = e * cosf(dti), li = e * sinf(dti);
    float m    = Ar * Ar + Ai * Ai;
    float inv  = 1.0f / m;
    float numr = lr - 1.0f, numi = li;
    float br   = (numr * Ar + numi * Ai) * inv;
    float bi   = (numi * Ar - numr * Ai) * inv;
    float cre  = C_re[idx], cim = C_im[idx];
    lam[idx]  = make_float2(lr, li);
    dta[idx]  = make_float2(dtr, dti);
    cb2[idx]  = make_float2(2.0f * (cre * br - cim * bi),
                            2.0f * (cre * bi + cim * br));
    float eT = expf(64.0f * dtr);
    lamT[idx] = make_float2(eT * cosf(64.0f * dti), eT * sinf(64.0f * dti));
}

// ---------------------------------------------------------------------------
// P1: Kloc[d][c][delta] = Re sum_n cb2_n lam_n^delta   (delta = 0..63)
// ---------------------------------------------------------------------------
__global__ __launch_bounds__(64) void p1_kernel(
    const float2* __restrict__ cb2, const float2* __restrict__ lam,
    float* __restrict__ Kloc)
{
    __shared__ float st[64 * 65];
    int d = blockIdx.y, c = blockIdx.x, n = threadIdx.x;
    float2 p = cb2[(d * CC + c) * NN + n];
    float2 l = lam[(d * CC + c) * NN + n];
    for (int t = 0; t < 64; ++t) {
        st[t * 65 + n] = p.x;
        float nr = p.x * l.x - p.y * l.y;
        p.y = p.x * l.y + p.y * l.x;
        p.x = nr;
    }
    __syncthreads();
    float s = 0.0f;
#pragma unroll 16
    for (int j = 0; j < 64; ++j) s += st[n * 65 + j];
    Kloc[(d * CC + c) * 64 + n] = s;
}

// ---------------------------------------------------------------------------
// P2V: Vp packed [d][c][nf=8][ks=2][lane=64][e=8]: B[k][q]=Re/Im(lam_n^{63-k})
//      q = nf*16+(l&15), k = ks*32+(l>>4)*8+e, n = q>>1
// ---------------------------------------------------------------------------
__global__ __launch_bounds__(256) void p2v_kernel(
    const float2* __restrict__ dta, bf16* __restrict__ Vp)
{
    int t = blockIdx.x * 256 + threadIdx.x;
    int e = t & 7, l = (t >> 3) & 63, ks = (t >> 9) & 1;
    int nf = (t >> 10) & 7, c = (t >> 13) & 127, d = t >> 20;
    int q = nf * 16 + (l & 15);
    int k = ks * 32 + (l >> 4) * 8 + e;
    int n = q >> 1;
    float2 a = dta[(d * CC + c) * NN + n];
    float p  = (float)(63 - k);
    float mag = expf(p * a.x);
    float ang = p * a.y;
    float val = (q & 1) ? mag * sinf(ang) : mag * cosf(ang);
    Vp[t] = tobf(val);
}

// ---------------------------------------------------------------------------
// P2W: W2p packed [d][c][nf=4][ks=6][lane=64][e=8]:
//  k<64 : B[k][i] = Kloc[i-k] (k<=i) + (Dskip+1) on diag   (Toeplitz + skip)
//  k>=64: q=k-64, w = cb2_n * lam_n^{i+1}; B = (q odd ? -Im(w) : Re(w))
// ---------------------------------------------------------------------------
__global__ __launch_bounds__(256) void p2w_kernel(
    const float2* __restrict__ dta, const float2* __restrict__ cb2,
    const float* __restrict__ Kloc, const float* __restrict__ Dskip,
    bf16* __restrict__ W2p)
{
    int t = blockIdx.x * 256 + threadIdx.x;
    int e = t & 7, l = (t >> 3) & 63;
    int r = t >> 9;
    int ks = r % 6; r /= 6;
    int nf = r & 3; r >>= 2;
    int c  = r & 127;
    int d  = r >> 7;
    int i = nf * 16 + (l & 15);
    int k = ks * 32 + (l >> 4) * 8 + e;
    float val;
    if (k < 64) {
        val = (k <= i) ? Kloc[(d * CC + c) * 64 + (i - k)] : 0.0f;
        if (k == i) val += Dskip[d * CC + c] + 1.0f;
    } else {
        int q = k - 64, n = q >> 1;
        float2 a  = dta[(d * CC + c) * NN + n];
        float2 cb = cb2[(d * CC + c) * NN + n];
        float p   = (float)(i + 1);
        float mag = expf(p * a.x);
        float ang = p * a.y;
        float re = mag * cosf(ang), im = mag * sinf(ang);
        float wre = cb.x * re - cb.y * im;
        float wim = cb.x * im + cb.y * re;
        val = (q & 1) ? -wim : wre;
    }
    W2p[t] = tobf(val);
}

// ---------------------------------------------------------------------------
// x [B,L,C] fp32 -> xt [B][C][L] bf16
// ---------------------------------------------------------------------------
__global__ __launch_bounds__(256) void transpose_kernel(
    const float* __restrict__ x, bf16* __restrict__ xt)
{
    __shared__ float t[64][65];
    int ct = blockIdx.x, lt = blockIdx.y, b = blockIdx.z;
    int tx = threadIdx.x & 63, ty = threadIdx.x >> 6;
    const size_t xbase = ((size_t)b * LL + (size_t)lt * 64) * CC + (size_t)ct * 64;
#pragma unroll
    for (int i = 0; i < 16; ++i)
        t[ty + 4 * i][tx] = x[xbase + (size_t)(ty + 4 * i) * CC + tx];
    __syncthreads();
    const size_t obase = ((size_t)b * CC + (size_t)ct * 64) * LL + (size_t)lt * 64;
#pragma unroll
    for (int i = 0; i < 16; ++i)
        xt[obase + (size_t)(ty + 4 * i) * LL + tx] = tobf(t[tx][ty + 4 * i]);
}

// ---------------------------------------------------------------------------
// KS: fused per-(b,c) layer kernel. 4 waves.
//  phase1: Sloc[64 chunk x 128 q] = X @ Vp     (MFMA, K=64) -> LDS
//  phase2: wave0 scans chunks: s_k = lamT*s + P_k; Sprev -> LDS (bf16)
//  phase3: v[64 m x 64 i] = [x | Sprev] @ W2p  (MFMA, K=192) -> global bf16
// ---------------------------------------------------------------------------
__global__ __launch_bounds__(256) void ks_kernel(
    const bf16* __restrict__ u, bf16* __restrict__ v,
    const bf16* __restrict__ Vp, const bf16* __restrict__ W2p,
    const float2* __restrict__ lamT)
{
    int b = blockIdx.x, c = blockIdx.y;
    int w = threadIdx.x >> 6, l = threadIdx.x & 63;
    const bf16* xrow = u + ((size_t)(b * CC + c)) * LL;
    const bf16* Vpc  = Vp  + (size_t)c * 8192;
    const bf16* W2c  = W2p + (size_t)c * 12288;

    __shared__ float Sl[64 * 132];   // chunk-major, pad 132
    __shared__ bf16  Sp[64 * 136];   // chunk-major, pad 136 (272B rows)

    // ---- phase 1: Sloc = X @ Bv ----
    f32x4 acc[8];
#pragma unroll
    for (int nf = 0; nf < 8; ++nf) acc[nf] = (f32x4){0.f, 0.f, 0.f, 0.f};
    int arow = 16 * w + (l & 15);
    int koff = (l >> 4) * 8;
#pragma unroll
    for (int ks = 0; ks < 2; ++ks) {
        short8 af = *(const short8*)(xrow + arow * 64 + ks * 32 + koff);
#pragma unroll
        for (int nf = 0; nf < 8; ++nf) {
            short8 bf = *(const short8*)(Vpc + (((nf * 2 + ks) * 64) + l) * 8);
            acc[nf] = MFMA(af, bf, acc[nf]);
        }
    }
#pragma unroll
    for (int nf = 0; nf < 8; ++nf) {
#pragma unroll
        for (int j = 0; j < 4; ++j) {
            int row = 16 * w + (l >> 4) * 4 + j;
            Sl[row * 132 + nf * 16 + (l & 15)] = acc[nf][j];
        }
    }
    __syncthreads();

    // ---- phase 2: serial chunk scan (wave 0; lane = mode n) ----
    if (w == 0) {
        float2 lt = lamT[c * NN + l];
        float sr = 0.f, si = 0.f;
        for (int k = 0; k < 64; ++k) {
            Sp[k * 136 + 2 * l]     = tobf(sr);
            Sp[k * 136 + 2 * l + 1] = tobf(si);
            float pr = Sl[k * 132 + 2 * l];
            float pi = Sl[k * 132 + 2 * l + 1];
            float nr = fmaf(lt.x, sr, fmaf(-lt.y, si, pr));
            si = fmaf(lt.x, si, fmaf(lt.y, sr, pi));
            sr = nr;
        }
    }
    __syncthreads();

    // ---- phase 3: out = [x | Sprev] @ W2 (K=192) ----
    f32x4 o[4];
#pragma unroll
    for (int nf = 0; nf < 4; ++nf) o[nf] = (f32x4){0.f, 0.f, 0.f, 0.f};
#pragma unroll
    for (int ks = 0; ks < 6; ++ks) {
        short8 af;
        if (ks < 2)
            af = *(const short8*)(xrow + arow * 64 + ks * 32 + koff);
        else
            af = *(const short8*)(&Sp[arow * 136 + (ks - 2) * 32 + koff]);
#pragma unroll
        for (int nf = 0; nf < 4; ++nf) {
            short8 bf = *(const short8*)(W2c + (((nf * 6 + ks) * 64) + l) * 8);
            o[nf] = MFMA(af, bf, o[nf]);
        }
    }
    bf16* vrow = v + ((size_t)(b * CC + c)) * LL;
#pragma unroll
    for (int nf = 0; nf < 4; ++nf) {
#pragma unroll
        for (int j = 0; j < 4; ++j) {
            int m = 16 * w + (l >> 4) * 4 + j;
            vrow[m * 64 + nf * 16 + (l & 15)] = tobf(o[nf][j]);
        }
    }
}

// ---------------------------------------------------------------------------
// LayerNorm over C (bf16 in/out); final layer fuses head projection (fp32 out)
// ---------------------------------------------------------------------------
__global__ __launch_bounds__(256) void ln_kernel(
    const bf16* __restrict__ v, bf16* __restrict__ outx,
    const float* __restrict__ w, const float* __restrict__ bta,
    const float* __restrict__ headw, const float* __restrict__ headb,
    float* __restrict__ fout, int isfinal)
{
    __shared__ float tile[CC][65];
    __shared__ float r1[4][64];
    __shared__ float r2[4][64];
    __shared__ float mrs[2][64];
    int b    = blockIdx.y;
    int l0   = blockIdx.x * 64;
    int lane = threadIdx.x & 63;
    int cg   = threadIdx.x >> 6;
    float sum = 0.0f, sq = 0.0f;
#pragma unroll
    for (int ci = 0; ci < 32; ++ci) {
        int c = cg * 32 + ci;
        float val = __bfloat162float(v[((size_t)b * CC + c) * LL + l0 + lane]);
        tile[c][lane] = val;
        sum += val;
        sq = fmaf(val, val, sq);
    }
    r1[cg][lane] = sum;
    r2[cg][lane] = sq;
    __syncthreads();
    if (cg == 0) {
        float s = r1[0][lane] + r1[1][lane] + r1[2][lane] + r1[3][lane];
        float q = r2[0][lane] + r2[1][lane] + r2[2][lane] + r2[3][lane];
        float mean = s * (1.0f / CC);
        float var  = q * (1.0f / CC) - mean * mean;
        mrs[0][lane] = mean;
        mrs[1][lane] = rsqrtf(var + EPSV);
    }
    __syncthreads();
    float mean = mrs[0][lane], rstd = mrs[1][lane];
    if (!isfinal) {
#pragma unroll
        for (int ci = 0; ci < 32; ++ci) {
            int c = cg * 32 + ci;
            float o = (tile[c][lane] - mean) * rstd * w[c] + bta[c];
            outx[((size_t)b * CC + c) * LL + l0 + lane] = tobf(o);
        }
    } else {
        float h = 0.0f;
#pragma unroll
        for (int ci = 0; ci < 32; ++ci) {
            int c = cg * 32 + ci;
            float o = (tile[c][lane] - mean) * rstd * w[c] + bta[c];
            h = fmaf(o, headw[c], h);
        }
        __syncthreads();
        r1[cg][lane] = h;
        __syncthreads();
        if (cg == 0)
            fout[(size_t)b * LL + l0 + lane] =
                r1[0][lane] + r1[1][lane] + r1[2][lane] + r1[3][lane] + headb[0];
    }
}

// ---------------------------------------------------------------------------
extern "C" void kernel_launch(void* const* d_in, const int* in_sizes, int n_in,
                              void* d_out, int out_size, void* d_ws, size_t ws_size,
                              hipStream_t stream)
{
    const float* x      = (const float*)d_in[0];
    const float* log_dt = (const float*)d_in[1];
    const float* A_real = (const float*)d_in[2];
    const float* A_imag = (const float*)d_in[3];
    const float* C_re   = (const float*)d_in[4];
    const float* C_im   = (const float*)d_in[5];
    const float* Dskip  = (const float*)d_in[6];
    const float* norm_w = (const float*)d_in[7];
    const float* norm_b = (const float*)d_in[8];
    const float* head_w = (const float*)d_in[9];
    const float* head_b = (const float*)d_in[10];
    float* out = (float*)d_out;

    const size_t DCN = (size_t)DEPTH_ * CC * NN;          // 32768
    const size_t BCL = (size_t)BB * CC * LL;              // 16.78M

    float2* lam  = (float2*)d_ws;
    float2* dta  = lam + DCN;
    float2* cb2  = dta + DCN;
    float2* lamT = cb2 + DCN;
    float*  Kloc = (float*)(lamT + DCN);                  // D*C*64
    bf16*   u    = (bf16*)(Kloc + (size_t)DEPTH_ * CC * 64);
    bf16*   v    = u + BCL;
    bf16*   Vp   = v + BCL;                               // D*C*8192
    bf16*   W2p  = Vp + (size_t)DEPTH_ * CC * 8192;       // D*C*12288
    // total ~= 90 MB

    p0_kernel<<<dim3(CC, DEPTH_), 64, 0, stream>>>(
        log_dt, A_real, A_imag, C_re, C_im, lam, dta, cb2, lamT);
    p1_kernel<<<dim3(CC, DEPTH_), 64, 0, stream>>>(cb2, lam, Kloc);
    p2v_kernel<<<(DEPTH_ * CC * 8192) / 256, 256, 0, stream>>>(dta, Vp);
    p2w_kernel<<<(DEPTH_ * CC * 12288) / 256, 256, 0, stream>>>(
        dta, cb2, Kloc, Dskip, W2p);
    transpose_kernel<<<dim3(CC / 64, LL / 64, BB), 256, 0, stream>>>(x, u);

    for (int d = 0; d < DEPTH_; ++d) {
        ks_kernel<<<dim3(BB, CC), 256, 0, stream>>>(
            u, v, Vp + (size_t)d * CC * 8192, W2p + (size_t)d * CC * 12288,
            lamT + (size_t)d * CC * NN);
        ln_kernel<<<dim3(LL / 64, BB), 256, 0, stream>>>(
            v, u, norm_w + d * CC, norm_b + d * CC,
            head_w, head_b, out, (d == DEPTH_ - 1) ? 1 : 0);
    }
}

// Round 3
// 247.944 us; speedup vs baseline: 5.6886x; 1.1420x over previous
//
#include <hip/hip_runtime.h>
#include <hip/hip_bf16.h>

// S4D regressor, chunked-scan MFMA formulation (R3: wave-parallel scan,
// swapped-operand MFMA for vectorized epilogues, LDS diet -> 4 blocks/CU).
// B=32, L=4096, C=128, N=64, DEPTH=4, OUT=1.

#define BB     32
#define LL     4096
#define CC     128
#define NN     64
#define DEPTH_ 4
#define EPSV   1e-5f

#define SLP    132          // Sl row stride (floats), 16B-aligned rows

typedef __attribute__((ext_vector_type(8))) short short8;
typedef __attribute__((ext_vector_type(4))) short short4v;
typedef __attribute__((ext_vector_type(4))) float f32x4;
typedef __hip_bfloat16 bf16;

#define MFMA(a, b, c) __builtin_amdgcn_mfma_f32_16x16x32_bf16(a, b, c, 0, 0, 0)

__device__ __forceinline__ bf16 tobf(float x) { return __float2bfloat16(x); }
__device__ __forceinline__ short bfbits(float x) {
    union { bf16 b; short s; } u; u.b = __float2bfloat16(x); return u.s;
}

// ---------------------------------------------------------------------------
// P0: per (d,c,n): lam=exp(dt*A), dta=dt*A, cb2=2*C*(lam-1)/A, lamT=lam^64
// ---------------------------------------------------------------------------
__global__ __launch_bounds__(64) void p0_kernel(
    const float* __restrict__ log_dt, const float* __restrict__ A_real,
    const float* __restrict__ A_imag, const float* __restrict__ C_re,
    const float* __restrict__ C_im, float2* __restrict__ lam,
    float2* __restrict__ dta, float2* __restrict__ cb2,
    float2* __restrict__ lamT)
{
    int d = blockIdx.y, c = blockIdx.x, n = threadIdx.x;
    int idx = (d * CC + c) * NN + n;
    float dt  = expf(log_dt[d * CC + c]);
    float Ar  = -expf(A_real[idx]);
    float Ai  = A_imag[idx];
    float dtr = dt * Ar, dti = dt * Ai;
    float e   = expf(dtr);
    float lr  = e * cosf(dti), li = e * sinf(dti);
    float m    = Ar * Ar + Ai * Ai;
    float inv  = 1.0f / m;
    float numr = lr - 1.0f, numi = li;
    float br   = (numr * Ar + numi * Ai) * inv;
    float bi   = (numi * Ar - numr * Ai) * inv;
    float cre  = C_re[idx], cim = C_im[idx];
    lam[idx]  = make_float2(lr, li);
    dta[idx]  = make_float2(dtr, dti);
    cb2[idx]  = make_float2(2.0f * (cre * br - cim * bi),
                            2.0f * (cre * bi + cim * br));
    float eT = expf(64.0f * dtr);
    lamT[idx] = make_float2(eT * cosf(64.0f * dti), eT * sinf(64.0f * dti));
}

// ---------------------------------------------------------------------------
// P1: Kloc[d][c][delta] = Re sum_n cb2_n lam_n^delta   (delta = 0..63)
// ---------------------------------------------------------------------------
__global__ __launch_bounds__(64) void p1_kernel(
    const float2* __restrict__ cb2, const float2* __restrict__ lam,
    float* __restrict__ Kloc)
{
    __shared__ float st[64 * 65];
    int d = blockIdx.y, c = blockIdx.x, n = threadIdx.x;
    float2 p = cb2[(d * CC + c) * NN + n];
    float2 l = lam[(d * CC + c) * NN + n];
    for (int t = 0; t < 64; ++t) {
        st[t * 65 + n] = p.x;
        float nr = p.x * l.x - p.y * l.y;
        p.y = p.x * l.y + p.y * l.x;
        p.x = nr;
    }
    __syncthreads();
    float s = 0.0f;
#pragma unroll 16
    for (int j = 0; j < 64; ++j) s += st[n * 65 + j];
    Kloc[(d * CC + c) * 64 + n] = s;
}

// ---------------------------------------------------------------------------
// P2V: Vp packed [d][c][nf=8][ks=2][lane=64][e=8]: B[k][q]=Re/Im(lam_n^{63-k})
// ---------------------------------------------------------------------------
__global__ __launch_bounds__(256) void p2v_kernel(
    const float2* __restrict__ dta, bf16* __restrict__ Vp)
{
    int t = blockIdx.x * 256 + threadIdx.x;
    int e = t & 7, l = (t >> 3) & 63, ks = (t >> 9) & 1;
    int nf = (t >> 10) & 7, c = (t >> 13) & 127, d = t >> 20;
    int q = nf * 16 + (l & 15);
    int k = ks * 32 + (l >> 4) * 8 + e;
    int n = q >> 1;
    float2 a = dta[(d * CC + c) * NN + n];
    float p  = (float)(63 - k);
    float mag = expf(p * a.x);
    float ang = p * a.y;
    float val = (q & 1) ? mag * sinf(ang) : mag * cosf(ang);
    Vp[t] = tobf(val);
}

// ---------------------------------------------------------------------------
// P2W: W2p packed [d][c][nf=4][ks=6][lane=64][e=8]
// ---------------------------------------------------------------------------
__global__ __launch_bounds__(256) void p2w_kernel(
    const float2* __restrict__ dta, const float2* __restrict__ cb2,
    const float* __restrict__ Kloc, const float* __restrict__ Dskip,
    bf16* __restrict__ W2p)
{
    int t = blockIdx.x * 256 + threadIdx.x;
    int e = t & 7, l = (t >> 3) & 63;
    int r = t >> 9;
    int ks = r % 6; r /= 6;
    int nf = r & 3; r >>= 2;
    int c  = r & 127;
    int d  = r >> 7;
    int i = nf * 16 + (l & 15);
    int k = ks * 32 + (l >> 4) * 8 + e;
    float val;
    if (k < 64) {
        val = (k <= i) ? Kloc[(d * CC + c) * 64 + (i - k)] : 0.0f;
        if (k == i) val += Dskip[d * CC + c] + 1.0f;
    } else {
        int q = k - 64, n = q >> 1;
        float2 a  = dta[(d * CC + c) * NN + n];
        float2 cb = cb2[(d * CC + c) * NN + n];
        float p   = (float)(i + 1);
        float mag = expf(p * a.x);
        float ang = p * a.y;
        float re = mag * cosf(ang), im = mag * sinf(ang);
        float wre = cb.x * re - cb.y * im;
        float wim = cb.x * im + cb.y * re;
        val = (q & 1) ? -wim : wre;
    }
    W2p[t] = tobf(val);
}

// ---------------------------------------------------------------------------
// x [B,L,C] fp32 -> xt [B][C][L] bf16
// ---------------------------------------------------------------------------
__global__ __launch_bounds__(256) void transpose_kernel(
    const float* __restrict__ x, bf16* __restrict__ xt)
{
    __shared__ float t[64][65];
    int ct = blockIdx.x, lt = blockIdx.y, b = blockIdx.z;
    int tx = threadIdx.x & 63, ty = threadIdx.x >> 6;
    const size_t xbase = ((size_t)b * LL + (size_t)lt * 64) * CC + (size_t)ct * 64;
#pragma unroll
    for (int i = 0; i < 16; ++i)
        t[ty + 4 * i][tx] = x[xbase + (size_t)(ty + 4 * i) * CC + tx];
    __syncthreads();
    const size_t obase = ((size_t)b * CC + (size_t)ct * 64) * LL + (size_t)lt * 64;
#pragma unroll
    for (int i = 0; i < 16; ++i)
        xt[obase + (size_t)(ty + 4 * i) * LL + tx] = tobf(t[tx][ty + 4 * i]);
}

// ---------------------------------------------------------------------------
// KS: fused per-(b,c) layer kernel, 4 waves, wave-parallel scan.
//  ph1: Sl[m][q] = (Vp^T x)         swapped MFMA: lane col = chunk m
//  ph2: each wave scans its 16 chunks in regs; carries via LDS; Sp (bf16)
//       overlays Sl.
//  ph3: v[i][m] = (W2^T [x|Sp])     swapped MFMA -> short4 global stores
// ---------------------------------------------------------------------------
__global__ __launch_bounds__(256, 4) void ks_kernel(
    const bf16* __restrict__ u, bf16* __restrict__ v,
    const bf16* __restrict__ Vp, const bf16* __restrict__ W2p,
    const float2* __restrict__ lamT)
{
    int b = blockIdx.x, c = blockIdx.y;
    int w = threadIdx.x >> 6, l = threadIdx.x & 63;
    const bf16* xrow = u + ((size_t)(b * CC + c)) * LL;
    const bf16* Vpc  = Vp  + (size_t)c * 8192;
    const bf16* W2c  = W2p + (size_t)c * 12288;

    __shared__ float Sl[64 * SLP + 4 * SLP];   // 35.9 KB; Sp/cbuf carved out
    float* cbuf = Sl + 64 * SLP;
    bf16*  Sp   = (bf16*)Sl;                   // overlays Sl after scan

    const int m    = 16 * w + (l & 15);        // this lane's chunk (as B col)
    const int koff = (l >> 4) * 8;

    // ---- phase 1: Sl[m][q] = sum_k Vp[k][q] * x[m][k]  (K=64) ----
    short8 xf0 = *(const short8*)(xrow + m * 64 + koff);
    short8 xf1 = *(const short8*)(xrow + m * 64 + 32 + koff);
    f32x4 acc[8];
#pragma unroll
    for (int nf = 0; nf < 8; ++nf) acc[nf] = (f32x4){0.f, 0.f, 0.f, 0.f};
#pragma unroll
    for (int nf = 0; nf < 8; ++nf) {
        short8 vf0 = *(const short8*)(Vpc + ((nf * 2 + 0) * 64 + l) * 8);
        short8 vf1 = *(const short8*)(Vpc + ((nf * 2 + 1) * 64 + l) * 8);
        acc[nf] = MFMA(vf0, xf0, acc[nf]);
        acc[nf] = MFMA(vf1, xf1, acc[nf]);
    }
#pragma unroll
    for (int nf = 0; nf < 8; ++nf)
        *(f32x4*)(&Sl[m * SLP + nf * 16 + (l >> 4) * 4]) = acc[nf];
    __syncthreads();

    // ---- phase 2a: local scan (lane = mode, wave w owns chunks 16w..16w+15)
    float2 lt = lamT[c * NN + l];
    float lpr[16], lpi[16];
    float sr = 0.f, si = 0.f;
#pragma unroll
    for (int k = 0; k < 16; ++k) {
        lpr[k] = sr; lpi[k] = si;
        float pr = Sl[(16 * w + k) * SLP + 2 * l];
        float pi = Sl[(16 * w + k) * SLP + 2 * l + 1];
        float nr = fmaf(lt.x, sr, fmaf(-lt.y, si, pr));
        si = fmaf(lt.x, si, fmaf(lt.y, sr, pi));
        sr = nr;
    }
    cbuf[w * SLP + 2 * l]     = sr;     // wave total T_w
    cbuf[w * SLP + 2 * l + 1] = si;
    __syncthreads();

    // ---- phase 2b: carry combine + rebuild Sprev, write bf16 (over Sl) ----
    // lamT^16, lamT^32 by repeated squaring
    float ar = lt.x, ai = lt.y;
#pragma unroll
    for (int s = 0; s < 4; ++s) {
        float na = ar * ar - ai * ai; ai = 2.f * ar * ai; ar = na;
    }
    float a2r = ar * ar - ai * ai, a2i = 2.f * ar * ai;   // lamT^32
    float cr = 0.f, ci = 0.f;
    if (w >= 1) {
        float t0r = cbuf[2 * l], t0i = cbuf[2 * l + 1];
        if (w == 1) { cr = t0r; ci = t0i; }
        else if (w == 2) {
            cr = ar * t0r - ai * t0i + cbuf[SLP + 2 * l];
            ci = ar * t0i + ai * t0r + cbuf[SLP + 2 * l + 1];
        } else {
            float t1r = cbuf[SLP + 2 * l], t1i = cbuf[SLP + 2 * l + 1];
            cr = a2r * t0r - a2i * t0i + ar * t1r - ai * t1i + cbuf[2 * SLP + 2 * l];
            ci = a2r * t0i + a2i * t0r + ar * t1i + ai * t1r + cbuf[2 * SLP + 2 * l + 1];
        }
    }
    __syncthreads();                 // all Sl reads done; safe to overlay Sp
#pragma unroll
    for (int k = 0; k < 16; ++k) {
        float spr = lpr[k] + cr;
        float spi = lpi[k] + ci;
        union { short2 s2; uint u32; } pk;
        pk.s2.x = bfbits(spr); pk.s2.y = bfbits(spi);
        *(uint*)(&Sp[(16 * w + k) * 136 + 2 * l]) = pk.u32;
        float ncr = cr * lt.x - ci * lt.y;
        ci = cr * lt.y + ci * lt.x;
        cr = ncr;
    }
    __syncthreads();

    // ---- phase 3: v[i][m] = sum_k W2[k][i] * [x|Sp][m][k]  (K=192) ----
    f32x4 o[4];
#pragma unroll
    for (int nf = 0; nf < 4; ++nf) o[nf] = (f32x4){0.f, 0.f, 0.f, 0.f};
#pragma unroll
    for (int ks = 0; ks < 6; ++ks) {
        short8 xf;
        if (ks == 0)      xf = xf0;
        else if (ks == 1) xf = xf1;
        else              xf = *(const short8*)(&Sp[m * 136 + (ks - 2) * 32 + koff]);
#pragma unroll
        for (int nf = 0; nf < 4; ++nf) {
            short8 wf = *(const short8*)(W2c + ((nf * 6 + ks) * 64 + l) * 8);
            o[nf] = MFMA(wf, xf, o[nf]);
        }
    }
    bf16* vrow = v + ((size_t)(b * CC + c)) * LL;
#pragma unroll
    for (int nf = 0; nf < 4; ++nf) {
        short4v t;
        t[0] = bfbits(o[nf][0]); t[1] = bfbits(o[nf][1]);
        t[2] = bfbits(o[nf][2]); t[3] = bfbits(o[nf][3]);
        *(short4v*)(vrow + m * 64 + nf * 16 + (l >> 4) * 4) = t;
    }
}

// ---------------------------------------------------------------------------
// LayerNorm over C (bf16 in/out); final layer fuses head projection (fp32 out)
// ---------------------------------------------------------------------------
__global__ __launch_bounds__(256) void ln_kernel(
    const bf16* __restrict__ v, bf16* __restrict__ outx,
    const float* __restrict__ w, const float* __restrict__ bta,
    const float* __restrict__ headw, const float* __restrict__ headb,
    float* __restrict__ fout, int isfinal)
{
    __shared__ float tile[CC][65];
    __shared__ float r1[4][64];
    __shared__ float r2[4][64];
    __shared__ float mrs[2][64];
    int b    = blockIdx.y;
    int l0   = blockIdx.x * 64;
    int lane = threadIdx.x & 63;
    int cg   = threadIdx.x >> 6;
    float sum = 0.0f, sq = 0.0f;
#pragma unroll
    for (int ci = 0; ci < 32; ++ci) {
        int c = cg * 32 + ci;
        float val = __bfloat162float(v[((size_t)b * CC + c) * LL + l0 + lane]);
        tile[c][lane] = val;
        sum += val;
        sq = fmaf(val, val, sq);
    }
    r1[cg][lane] = sum;
    r2[cg][lane] = sq;
    __syncthreads();
    if (cg == 0) {
        float s = r1[0][lane] + r1[1][lane] + r1[2][lane] + r1[3][lane];
        float q = r2[0][lane] + r2[1][lane] + r2[2][lane] + r2[3][lane];
        float mean = s * (1.0f / CC);
        float var  = q * (1.0f / CC) - mean * mean;
        mrs[0][lane] = mean;
        mrs[1][lane] = rsqrtf(var + EPSV);
    }
    __syncthreads();
    float mean = mrs[0][lane], rstd = mrs[1][lane];
    if (!isfinal) {
#pragma unroll
        for (int ci = 0; ci < 32; ++ci) {
            int c = cg * 32 + ci;
            float o = (tile[c][lane] - mean) * rstd * w[c] + bta[c];
            outx[((size_t)b * CC + c) * LL + l0 + lane] = tobf(o);
        }
    } else {
        float h = 0.0f;
#pragma unroll
        for (int ci = 0; ci < 32; ++ci) {
            int c = cg * 32 + ci;
            float o = (tile[c][lane] - mean) * rstd * w[c] + bta[c];
            h = fmaf(o, headw[c], h);
        }
        __syncthreads();
        r1[cg][lane] = h;
        __syncthreads();
        if (cg == 0)
            fout[(size_t)b * LL + l0 + lane] =
                r1[0][lane] + r1[1][lane] + r1[2][lane] + r1[3][lane] + headb[0];
    }
}

// ---------------------------------------------------------------------------
extern "C" void kernel_launch(void* const* d_in, const int* in_sizes, int n_in,
                              void* d_out, int out_size, void* d_ws, size_t ws_size,
                              hipStream_t stream)
{
    const float* x      = (const float*)d_in[0];
    const float* log_dt = (const float*)d_in[1];
    const float* A_real = (const float*)d_in[2];
    const float* A_imag = (const float*)d_in[3];
    const float* C_re   = (const float*)d_in[4];
    const float* C_im   = (const float*)d_in[5];
    const float* Dskip  = (const float*)d_in[6];
    const float* norm_w = (const float*)d_in[7];
    const float* norm_b = (const float*)d_in[8];
    const float* head_w = (const float*)d_in[9];
    const float* head_b = (const float*)d_in[10];
    float* out = (float*)d_out;

    const size_t DCN = (size_t)DEPTH_ * CC * NN;
    const size_t BCL = (size_t)BB * CC * LL;

    float2* lam  = (float2*)d_ws;
    float2* dta  = lam + DCN;
    float2* cb2  = dta + DCN;
    float2* lamT = cb2 + DCN;
    float*  Kloc = (float*)(lamT + DCN);
    bf16*   u    = (bf16*)(Kloc + (size_t)DEPTH_ * CC * 64);
    bf16*   v    = u + BCL;
    bf16*   Vp   = v + BCL;
    bf16*   W2p  = Vp + (size_t)DEPTH_ * CC * 8192;

    p0_kernel<<<dim3(CC, DEPTH_), 64, 0, stream>>>(
        log_dt, A_real, A_imag, C_re, C_im, lam, dta, cb2, lamT);
    p1_kernel<<<dim3(CC, DEPTH_), 64, 0, stream>>>(cb2, lam, Kloc);
    p2v_kernel<<<(DEPTH_ * CC * 8192) / 256, 256, 0, stream>>>(dta, Vp);
    p2w_kernel<<<(DEPTH_ * CC * 12288) / 256, 256, 0, stream>>>(
        dta, cb2, Kloc, Dskip, W2p);
    transpose_kernel<<<dim3(CC / 64, LL / 64, BB), 256, 0, stream>>>(x, u);

    for (int d = 0; d < DEPTH_; ++d) {
        ks_kernel<<<dim3(BB, CC), 256, 0, stream>>>(
            u, v, Vp + (size_t)d * CC * 8192, W2p + (size_t)d * CC * 12288,
            lamT + (size_t)d * CC * NN);
        ln_kernel<<<dim3(LL / 64, BB), 256, 0, stream>>>(
            v, u, norm_w + d * CC, norm_b + d * CC,
            head_w, head_b, out, (d == DEPTH_ - 1) ? 1 : 0);
    }
}